// Round 5
// baseline (1111.192 us; speedup 1.0000x reference)
//
#include <hip/hip_runtime.h>
#include <stdint.h>

typedef unsigned short u16;
using frag8 = __attribute__((ext_vector_type(8))) short;
using f32x4 = __attribute__((ext_vector_type(4))) float;

#define NTOK 32768
#define FDIM 512

__device__ __forceinline__ float bflo(uint32_t p){ union{uint32_t u; float f;} v; v.u = p<<16; return v.f; }
__device__ __forceinline__ float bfhi(uint32_t p){ union{uint32_t u; float f;} v; v.u = p & 0xffff0000u; return v.f; }
__device__ __forceinline__ float bf1(u16 x){ union{uint32_t u; float f;} v; v.u = ((uint32_t)x)<<16; return v.f; }
__device__ __forceinline__ u16 f2bf(float f){
  union{float f; uint32_t u;} v; v.f = f;
  uint32_t u = v.u;
  u += 0x7fffu + ((u>>16)&1u);   // round-to-nearest-even
  return (u16)(u>>16);
}

__device__ __forceinline__ void async16(const void* g, void* l){
  __builtin_amdgcn_global_load_lds((const __attribute__((address_space(1))) uint32_t*)g,
                                   (__attribute__((address_space(3))) uint32_t*)l, 16, 0, 0);
}

// -------------------- embedding + positional encoding (bf16 x only) --------------------
__global__ __launch_bounds__(256) void embed_kernel(const int* __restrict__ text,
    const float* __restrict__ emb, const float* __restrict__ pe,
    u16* __restrict__ xb, const int tok0){
  const int gid = blockIdx.x*256 + threadIdx.x;
  const int base = gid*4;
  const int tl = base >> 9;
  const int f  = base & 511;
  const int tg = tl + tok0;
  const int s  = tg & 511;
  const int tok = text[tg];
  const float4 e4 = *(const float4*)(emb + (size_t)tok*FDIM + f);
  const float4 p4 = *(const float4*)(pe  + (size_t)s*FDIM + f);
  ushort4 ob;
  ob.x = f2bf(e4.x + p4.x);
  ob.y = f2bf(e4.y + p4.y);
  ob.z = f2bf(e4.z + p4.z);
  ob.w = f2bf(e4.w + p4.w);
  *(ushort4*)(xb + base) = ob;
}

// -------------------- weight transpose + fp32->bf16: WT[lay][n][k], n: Wq|Wk|Wv|Wf --------------------
__global__ __launch_bounds__(256) void transpose_w(const float* __restrict__ Wq,
    const float* __restrict__ Wk, const float* __restrict__ Wv, const float* __restrict__ Wf,
    u16* __restrict__ WT){
  const int gid = blockIdx.x*256 + threadIdx.x;
  const int n   = gid & 2047;
  const int k8  = (gid>>11) & 63;
  const int lay = gid >> 17;
  const float* src; int col;
  if      (n <  512){ src = Wq; col = n;      }
  else if (n < 1024){ src = Wk; col = n-512;  }
  else if (n < 1536){ src = Wv; col = n-1024; }
  else              { src = Wf; col = n-1536; }
  src += (size_t)lay*FDIM*FDIM;
  u16 vals[8] __attribute__((aligned(16)));
  #pragma unroll
  for (int i=0;i<8;i++) vals[i] = f2bf(src[(size_t)(k8*8+i)*FDIM + col]);
  *(int4*)(WT + ((size_t)lay*2048 + n)*FDIM + k8*8) = *(const int4*)vals;
}

// -------------------- 256x256 ring-4 pipelined MFMA GEMM (R1 structure, best measured) ----------
// QKV only: C = xb * WT^T + bias(q|k|v by column range), ldC=1536.
__global__ __launch_bounds__(512, 2) void gemm256(
    const u16* __restrict__ A, const u16* __restrict__ BT,
    const float* __restrict__ b0, const float* __restrict__ b1, const float* __restrict__ b2,
    u16* __restrict__ C, const int ldC, const int NB){
  __shared__ __attribute__((aligned(16))) short As[4*256*32];   // 64 KiB
  __shared__ __attribute__((aligned(16))) short Bs[4*256*32];   // 64 KiB
  const int nwg = gridDim.x;
  const int orig = blockIdx.x;
  const int wg = ((nwg & 7) == 0) ? ((orig & 7)*(nwg >> 3) + (orig >> 3)) : orig;
  const int nblk = wg % NB, mblk = wg / NB;
  const int m0 = mblk << 8, n0 = nblk << 8;
  const int tid = threadIdx.x;
  const int wid = tid >> 6, l = tid & 63;
  const int lm = l & 15, quad = l >> 4;

  const int srow = wid*16 + (l >> 2);
  const int sch  = (l & 3) ^ ((l >> 3) & 3);
  const char* Asrc0 = (const char*)A  + ((size_t)(m0 + srow))*1024 + sch*16;
  const char* Asrc1 = Asrc0 + 128*1024;
  const char* Bsrc0 = (const char*)BT + ((size_t)(n0 + srow))*1024 + sch*16;
  const char* Bsrc1 = Bsrc0 + 128*1024;
  char* ldsAw = (char*)As + wid*1024;
  char* ldsBw = (char*)Bs + wid*1024;

  f32x4 acc[8][4];
  #pragma unroll
  for (int i=0;i<8;i++)
    #pragma unroll
    for (int j=0;j<4;j++){ f32x4 z = {0.f,0.f,0.f,0.f}; acc[i][j] = z; }

  const int rsel = quad ^ ((lm >> 1) & 3);
  const int aB = ((wid>>2)*128 + lm)*32 + rsel*8;
  const int bB = ((wid&3)*64  + lm)*32 + rsel*8;

  #pragma unroll
  for (int kt=0; kt<3; kt++){
    async16(Asrc0 + kt*64, ldsAw + kt*16384);
    async16(Asrc1 + kt*64, ldsAw + kt*16384 + 8192);
    async16(Bsrc0 + kt*64, ldsBw + kt*16384);
    async16(Bsrc1 + kt*64, ldsBw + kt*16384 + 8192);
  }

  for (int t=0; t<16; ++t){
    if (t < 14)       asm volatile("s_waitcnt vmcnt(8)" ::: "memory");
    else if (t == 14) asm volatile("s_waitcnt vmcnt(4)" ::: "memory");
    else              asm volatile("s_waitcnt vmcnt(0)" ::: "memory");
    __builtin_amdgcn_s_barrier();
    asm volatile("" ::: "memory");
    const int slot = t & 3;
    const short* sA = As + slot*8192;
    const short* sB = Bs + slot*8192;
    frag8 af[4], bfrg[4], ag[4];
    #pragma unroll
    for (int mi=0; mi<4; mi++) af[mi] = *(const frag8*)(sA + aB + mi*512);
    #pragma unroll
    for (int nj=0; nj<4; nj++) bfrg[nj] = *(const frag8*)(sB + bB + nj*512);
    if (t < 13){
      const int s3 = (t+3) & 3, off = (t+3)*64;
      async16(Asrc0 + off, ldsAw + s3*16384);
      async16(Asrc1 + off, ldsAw + s3*16384 + 8192);
    }
    __builtin_amdgcn_s_setprio(1);
    #pragma unroll
    for (int mi=0; mi<4; mi++)
      #pragma unroll
      for (int nj=0; nj<4; nj++)
        acc[mi][nj] = __builtin_amdgcn_mfma_f32_16x16x32_bf16(af[mi], bfrg[nj], acc[mi][nj], 0,0,0);
    __builtin_amdgcn_s_setprio(0);
    #pragma unroll
    for (int mi=0; mi<4; mi++) ag[mi] = *(const frag8*)(sA + aB + 2048 + mi*512);
    if (t < 13){
      const int s3 = (t+3) & 3, off = (t+3)*64;
      async16(Bsrc0 + off, ldsBw + s3*16384);
      async16(Bsrc1 + off, ldsBw + s3*16384 + 8192);
    }
    __builtin_amdgcn_s_setprio(1);
    #pragma unroll
    for (int mi=0; mi<4; mi++)
      #pragma unroll
      for (int nj=0; nj<4; nj++)
        acc[4+mi][nj] = __builtin_amdgcn_mfma_f32_16x16x32_bf16(ag[mi], bfrg[nj], acc[4+mi][nj], 0,0,0);
    __builtin_amdgcn_s_setprio(0);
  }

  float bias[4]; int cols[4];
  #pragma unroll
  for (int nj=0;nj<4;nj++){
    const int c = n0 + (wid&3)*64 + nj*16 + lm;
    cols[nj] = c;
    bias[nj] = (c<512 ? b0[c] : (c<1024 ? b1[c-512] : b2[c-1024]));
  }
  #pragma unroll
  for (int mi=0; mi<8; mi++){
    const int rbase = m0 + (wid>>2)*128 + mi*16 + quad*4;
    #pragma unroll
    for (int r=0;r<4;r++){
      const size_t row = (size_t)(rbase + r);
      #pragma unroll
      for (int nj=0;nj<4;nj++){
        float v = acc[mi][nj][r] + bias[nj];
        C[row*(size_t)ldC + cols[nj]] = f2bf(v);
      }
    }
  }
}

// -------------------- per-token head-attention + residual(bf16) + LN1 (1 wave = 1 token) --------------------
__global__ __launch_bounds__(256) void attn_ln1(const u16* __restrict__ qkvb,
    const u16* __restrict__ xb, const float* __restrict__ gam, const float* __restrict__ bet,
    u16* __restrict__ y1b){
  __shared__ __attribute__((aligned(16))) u16 sQ[4][1536];
  __shared__ float sWt[4][64];
  const int tid = threadIdx.x, w = tid>>6, l = tid&63;
  const int t = blockIdx.x*4 + w;
  {
    const int4* src = (const int4*)(qkvb + (size_t)t*1536);
    int4* dst = (int4*)(&sQ[w][0]);
    #pragma unroll
    for (int i=0;i<3;i++) dst[i*64 + l] = src[i*64 + l];
  }
  __syncthreads();
  const int h = l>>3, g = l&7;
  const u16* qrow = &sQ[w][h*64];
  const u16* krow = &sQ[w][512 + g*64];
  float sc = 0.f;
  const int dstart = (l&31)*2;
  #pragma unroll
  for (int i=0;i<32;i++){
    const int d = (dstart + 2*i) & 63;
    const uint32_t qp = *(const uint32_t*)(qrow + d);
    const uint32_t kp = *(const uint32_t*)(krow + d);
    sc += bflo(qp)*bflo(kp) + bfhi(qp)*bfhi(kp);
  }
  float mx = sc;
  mx = fmaxf(mx, __shfl_xor(mx,1));
  mx = fmaxf(mx, __shfl_xor(mx,2));
  mx = fmaxf(mx, __shfl_xor(mx,4));
  const float e = __expf(sc - mx);
  float ssum = e;
  ssum += __shfl_xor(ssum,1);
  ssum += __shfl_xor(ssum,2);
  ssum += __shfl_xor(ssum,4);
  sWt[w][l] = e / ssum;
  __syncthreads();
  float wt[8];
  #pragma unroll
  for (int gg=0;gg<8;gg++) wt[gg] = sWt[w][h*8+gg];
  float att[8] = {0,0,0,0,0,0,0,0};
  const int d0 = (l&7)*8;
  #pragma unroll
  for (int gg=0;gg<8;gg++){
    const int4 vv = *(const int4*)(&sQ[w][1024 + gg*64 + d0]);
    const uint32_t* vp = (const uint32_t*)&vv;
    #pragma unroll
    for (int p=0;p<4;p++){
      att[2*p]   += wt[gg]*bflo(vp[p]);
      att[2*p+1] += wt[gg]*bfhi(vp[p]);
    }
  }
  const size_t rb = (size_t)t*FDIM + l*8;
  const int4 xv = *(const int4*)(xb + rb);
  const uint32_t* xp = (const uint32_t*)&xv;
  float y[8]; float s1=0.f, s2=0.f;
  #pragma unroll
  for (int p=0;p<4;p++){
    y[2*p]   = att[2*p]   + bflo(xp[p]);
    y[2*p+1] = att[2*p+1] + bfhi(xp[p]);
  }
  #pragma unroll
  for (int j=0;j<8;j++){ s1 += y[j]; s2 += y[j]*y[j]; }
  #pragma unroll
  for (int off=1; off<64; off<<=1){ s1 += __shfl_xor(s1,off); s2 += __shfl_xor(s2,off); }
  const float mean = s1*(1.f/512.f);
  const float var  = s2*(1.f/512.f) - mean*mean;
  const float rstd = rsqrtf(var + 1e-5f);
  const float4 g0 = *(const float4*)(gam + l*8);
  const float4 g1v = *(const float4*)(gam + l*8 + 4);
  const float4 b0v = *(const float4*)(bet + l*8);
  const float4 b1v = *(const float4*)(bet + l*8 + 4);
  float of[8];
  of[0]=(y[0]-mean)*rstd*g0.x + b0v.x;
  of[1]=(y[1]-mean)*rstd*g0.y + b0v.y;
  of[2]=(y[2]-mean)*rstd*g0.z + b0v.z;
  of[3]=(y[3]-mean)*rstd*g0.w + b0v.w;
  of[4]=(y[4]-mean)*rstd*g1v.x + b1v.x;
  of[5]=(y[5]-mean)*rstd*g1v.y + b1v.y;
  of[6]=(y[6]-mean)*rstd*g1v.z + b1v.z;
  of[7]=(y[7]-mean)*rstd*g1v.w + b1v.w;
  u16 ob[8] __attribute__((aligned(16)));
  #pragma unroll
  for (int j=0;j<8;j++) ob[j] = f2bf(of[j]);
  *(int4*)(y1b + rb) = *(const int4*)ob;
}

// -------------------- FF GEMM (128x512 tile, full rows) + bias + residual + LN2 fused --------------------
// z = y1*Wf^T + bf + y1 (unrounded f32), then LN2(z) -> bf16 xb (or fp32 out).
// Tile covers ALL 512 output cols -> LN2 row stats computed in-block (R4's verified epilogue pattern).
// Ring-3 counted-vmcnt K-loop (R3 structure): stage t+2 during t; vmcnt(5) steady (A=1 + B=4 loads/tile).
// LDS: A 3x8KB + B 3x32KB + 4KB LN scratch = 124 KiB -> 1 block/CU.
__global__ __launch_bounds__(512, 1) void gemm_ff_ln2(
    const u16* __restrict__ y1, const u16* __restrict__ WTf,
    const float* __restrict__ bfv,
    const float* __restrict__ g2, const float* __restrict__ be2,
    u16* __restrict__ xb, float* __restrict__ outp, const int final_){
  __shared__ __attribute__((aligned(16))) short As[3*128*32];   // 24 KiB
  __shared__ __attribute__((aligned(16))) short Bs[3*512*32];   // 96 KiB
  __shared__ float ln2S[128*8];                                 // 4 KiB
  const int m0 = blockIdx.x << 7;
  const int tid = threadIdx.x;
  const int wid = tid>>6, l = tid&63;
  const int lm = l&15, quad = l>>4;
  const int wm = wid>>2, wn = wid&3;          // wave grid: 2M x 4N; wave tile 64x128

  const int srow = wid*16 + (l>>2);
  const int sch  = (l&3) ^ ((l>>3)&3);
  const char* Asrc = (const char*)y1  + ((size_t)(m0 + srow))*1024 + sch*16;
  const char* Bsrc = (const char*)WTf + ((size_t)srow)*1024 + sch*16;
  char* ldsAw = (char*)As + wid*1024;
  char* ldsBw = (char*)Bs + wid*1024;

  f32x4 acc[4][8];
  #pragma unroll
  for (int i=0;i<4;i++)
    #pragma unroll
    for (int j=0;j<8;j++){ f32x4 z = {0.f,0.f,0.f,0.f}; acc[i][j] = z; }

  const int rsel = quad ^ ((lm>>1)&3);
  const int aB = (wm*64  + lm)*32 + rsel*8;   // shorts within 128x32 slot
  const int bB = (wn*128 + lm)*32 + rsel*8;   // shorts within 512x32 slot

  // prologue: stage tiles 0,1 (5 loads each)
  #pragma unroll
  for (int kt=0; kt<2; kt++){
    async16(Asrc + kt*64, ldsAw + kt*8192);
    #pragma unroll
    for (int r=0;r<4;r++)
      async16(Bsrc + (size_t)r*131072 + kt*64, ldsBw + kt*32768 + r*8192);
  }

#define FT(T_, DOSTAGE, VMC) { \
    asm volatile("s_waitcnt vmcnt(" #VMC ")" ::: "memory"); \
    __builtin_amdgcn_s_barrier(); \
    asm volatile("" ::: "memory"); \
    if (DOSTAGE){ const int s_=((T_)+2)%3; const int off_=((T_)+2)*64; \
      async16(Asrc + off_, ldsAw + s_*8192); \
      _Pragma("unroll") \
      for (int r_=0;r_<4;r_++) \
        async16(Bsrc + (size_t)r_*131072 + off_, ldsBw + s_*32768 + r_*8192); } \
    const short* sA_ = As + ((T_)%3)*4096; \
    const short* sB_ = Bs + ((T_)%3)*16384; \
    frag8 af_[4], bf_[8]; \
    _Pragma("unroll") \
    for (int x_=0;x_<4;x_++) af_[x_] = *(const frag8*)(sA_ + aB + x_*512); \
    _Pragma("unroll") \
    for (int x_=0;x_<8;x_++) bf_[x_] = *(const frag8*)(sB_ + bB + x_*512); \
    __builtin_amdgcn_s_setprio(1); \
    _Pragma("unroll") \
    for (int mi_=0;mi_<4;mi_++) \
      _Pragma("unroll") \
      for (int nj_=0;nj_<8;nj_++) \
        acc[mi_][nj_] = __builtin_amdgcn_mfma_f32_16x16x32_bf16(af_[mi_], bf_[nj_], acc[mi_][nj_], 0,0,0); \
    __builtin_amdgcn_s_setprio(0); }

  FT(0,1,5)  FT(1,1,5)  FT(2,1,5)  FT(3,1,5)
  FT(4,1,5)  FT(5,1,5)  FT(6,1,5)  FT(7,1,5)
  FT(8,1,5)  FT(9,1,5)  FT(10,1,5) FT(11,1,5)
  FT(12,1,5) FT(13,1,5) FT(14,0,5) FT(15,0,0)
#undef FT

  // ---- epilogue: bias + residual(y1, bf16) + LN2 on f32 z + write ----
  int cols[8]; float bia[8], gg2[8], bb2[8];
  #pragma unroll
  for (int nj=0;nj<8;nj++){
    const int c = wn*128 + nj*16 + lm;
    cols[nj] = c; bia[nj] = bfv[c]; gg2[nj] = g2[c]; bb2[nj] = be2[c];
  }
  #pragma unroll
  for (int mi=0;mi<4;mi++){
    #pragma unroll
    for (int r=0;r<4;r++){
      const int row_l = wm*64 + mi*16 + quad*4 + r;
      const size_t rg = (size_t)(m0 + row_l)*FDIM;
      #pragma unroll
      for (int nj=0;nj<8;nj++)
        acc[mi][nj][r] += bia[nj] + bf1(y1[rg + cols[nj]]);
    }
  }
  // per-(row, wn) partial sums -> LDS
  #pragma unroll
  for (int mi=0;mi<4;mi++){
    #pragma unroll
    for (int r=0;r<4;r++){
      const int row_l = wm*64 + mi*16 + quad*4 + r;
      float s1 = 0.f, s2 = 0.f;
      #pragma unroll
      for (int nj=0;nj<8;nj++){ const float v = acc[mi][nj][r]; s1 += v; s2 += v*v; }
      s1 += __shfl_xor(s1,1); s2 += __shfl_xor(s2,1);
      s1 += __shfl_xor(s1,2); s2 += __shfl_xor(s2,2);
      s1 += __shfl_xor(s1,4); s2 += __shfl_xor(s2,4);
      s1 += __shfl_xor(s1,8); s2 += __shfl_xor(s2,8);
      if (lm == 0){
        ln2S[row_l*8 + wn*2]     = s1;
        ln2S[row_l*8 + wn*2 + 1] = s2;
      }
    }
  }
  __syncthreads();
  #pragma unroll
  for (int mi=0;mi<4;mi++){
    #pragma unroll
    for (int r=0;r<4;r++){
      const int row_l = wm*64 + mi*16 + quad*4 + r;
      const float s1t = ln2S[row_l*8] + ln2S[row_l*8+2] + ln2S[row_l*8+4] + ln2S[row_l*8+6];
      const float s2t = ln2S[row_l*8+1] + ln2S[row_l*8+3] + ln2S[row_l*8+5] + ln2S[row_l*8+7];
      const float mean = s1t*(1.f/512.f);
      const float var  = s2t*(1.f/512.f) - mean*mean;
      const float rstd = rsqrtf(var + 1e-5f);
      const size_t rg = (size_t)(m0 + row_l)*FDIM;
      if (final_){
        #pragma unroll
        for (int nj=0;nj<8;nj++)
          outp[rg + cols[nj]] = (acc[mi][nj][r]-mean)*rstd*gg2[nj] + bb2[nj];
      } else {
        #pragma unroll
        for (int nj=0;nj<8;nj++)
          xb[rg + cols[nj]] = f2bf((acc[mi][nj][r]-mean)*rstd*gg2[nj] + bb2[nj]);
      }
    }
  }
}

extern "C" void kernel_launch(void* const* d_in, const int* in_sizes, int n_in,
                              void* d_out, int out_size, void* d_ws, size_t ws_size,
                              hipStream_t stream){
  const int*   text = (const int*)d_in[0];
  const float* emb = (const float*)d_in[1];
  const float* pe  = (const float*)d_in[2];
  const float* Wq  = (const float*)d_in[3];
  const float* bq  = (const float*)d_in[4];
  const float* Wk  = (const float*)d_in[5];
  const float* bk  = (const float*)d_in[6];
  const float* Wv  = (const float*)d_in[7];
  const float* bv  = (const float*)d_in[8];
  const float* g1  = (const float*)d_in[9];
  const float* be1 = (const float*)d_in[10];
  const float* Wf  = (const float*)d_in[11];
  const float* bf_ = (const float*)d_in[12];
  const float* g2  = (const float*)d_in[13];
  const float* be2 = (const float*)d_in[14];
  float* outp = (float*)d_out;               // reference output dtype = float32

  // ---- layout: WT 12.6 MB + per-token {xb 1024 + y1b 1024 + qkv 3072} = 5120 B
  const size_t wtB = (size_t)6*2048*512*2;
  int T = NTOK;
  while (T > 2048 && wtB + (size_t)T*5120 > ws_size) T >>= 1;

  char* ws = (char*)d_ws;
  u16*   WT  = (u16*)ws;
  char*  act = ws + wtB;
  u16*   xb  = (u16*)act;                       // T*1024 B (updated in place per layer)
  u16*   y1b = (u16*)(act + (size_t)T*1024);    // T*1024 B
  u16*   qkv = (u16*)(act + (size_t)T*2048);    // T*3072 B

  hipLaunchKernelGGL(transpose_w, dim3(3072), dim3(256), 0, stream, Wq, Wk, Wv, Wf, WT);

  const int chunks = NTOK / T;
  for (int c = 0; c < chunks; c++){
    const int tok0 = c*T;
    hipLaunchKernelGGL(embed_kernel, dim3(T/2), dim3(256), 0, stream, text, emb, pe, xb, tok0);
    for (int lay=0; lay<6; lay++){
      const u16* WTl = WT + (size_t)lay*2048*FDIM;
      hipLaunchKernelGGL(gemm256, dim3((T/256)*6), dim3(512), 0, stream,
          xb, WTl, bq + lay*FDIM, bk + lay*FDIM, bv + lay*FDIM, qkv, 1536, 6);
      hipLaunchKernelGGL(attn_ln1, dim3(T/4), dim3(256), 0, stream,
          qkv, xb, g1 + lay*FDIM, be1 + lay*FDIM, y1b);
      hipLaunchKernelGGL(gemm_ff_ln2, dim3(T/128), dim3(512), 0, stream,
          y1b, WTl + (size_t)1536*FDIM, bf_ + lay*FDIM,
          g2 + lay*FDIM, be2 + lay*FDIM,
          xb, outp + (size_t)tok0*FDIM, (lay==5)?1:0);
    }
  }
}

// Round 6
// 882.779 us; speedup vs baseline: 1.2587x; 1.2587x over previous
//
#include <hip/hip_runtime.h>
#include <stdint.h>

typedef unsigned short u16;
using frag8 = __attribute__((ext_vector_type(8))) short;
using f32x4 = __attribute__((ext_vector_type(4))) float;

#define NTOK 32768
#define FDIM 512

__device__ __forceinline__ float bflo(uint32_t p){ union{uint32_t u; float f;} v; v.u = p<<16; return v.f; }
__device__ __forceinline__ float bfhi(uint32_t p){ union{uint32_t u; float f;} v; v.u = p & 0xffff0000u; return v.f; }
__device__ __forceinline__ float bf1(u16 x){ union{uint32_t u; float f;} v; v.u = ((uint32_t)x)<<16; return v.f; }
__device__ __forceinline__ u16 f2bf(float f){
  union{float f; uint32_t u;} v; v.f = f;
  uint32_t u = v.u;
  u += 0x7fffu + ((u>>16)&1u);   // round-to-nearest-even
  return (u16)(u>>16);
}

__device__ __forceinline__ void async16(const void* g, void* l){
  __builtin_amdgcn_global_load_lds((const __attribute__((address_space(1))) uint32_t*)g,
                                   (__attribute__((address_space(3))) uint32_t*)l, 16, 0, 0);
}

// -------------------- embedding + positional encoding (bf16 x only) --------------------
__global__ __launch_bounds__(256) void embed_kernel(const int* __restrict__ text,
    const float* __restrict__ emb, const float* __restrict__ pe,
    u16* __restrict__ xb, const int tok0){
  const int gid = blockIdx.x*256 + threadIdx.x;
  const int base = gid*4;
  const int tl = base >> 9;
  const int f  = base & 511;
  const int tg = tl + tok0;
  const int s  = tg & 511;
  const int tok = text[tg];
  const float4 e4 = *(const float4*)(emb + (size_t)tok*FDIM + f);
  const float4 p4 = *(const float4*)(pe  + (size_t)s*FDIM + f);
  ushort4 ob;
  ob.x = f2bf(e4.x + p4.x);
  ob.y = f2bf(e4.y + p4.y);
  ob.z = f2bf(e4.z + p4.z);
  ob.w = f2bf(e4.w + p4.w);
  *(ushort4*)(xb + base) = ob;
}

// -------------------- weight transpose + fp32->bf16: WT[lay][n][k], n: Wq|Wk|Wv|Wf --------------------
__global__ __launch_bounds__(256) void transpose_w(const float* __restrict__ Wq,
    const float* __restrict__ Wk, const float* __restrict__ Wv, const float* __restrict__ Wf,
    u16* __restrict__ WT){
  const int gid = blockIdx.x*256 + threadIdx.x;
  const int n   = gid & 2047;
  const int k8  = (gid>>11) & 63;
  const int lay = gid >> 17;
  const float* src; int col;
  if      (n <  512){ src = Wq; col = n;      }
  else if (n < 1024){ src = Wk; col = n-512;  }
  else if (n < 1536){ src = Wv; col = n-1024; }
  else              { src = Wf; col = n-1536; }
  src += (size_t)lay*FDIM*FDIM;
  u16 vals[8] __attribute__((aligned(16)));
  #pragma unroll
  for (int i=0;i<8;i++) vals[i] = f2bf(src[(size_t)(k8*8+i)*FDIM + col]);
  *(int4*)(WT + ((size_t)lay*2048 + n)*FDIM + k8*8) = *(const int4*)vals;
}

// -------------------- 256x256 8-phase pipelined MFMA GEMM (m201-style, BK=64, 2 K-tiles/iter) ----
// LDS per operand: 2 bufs x [kwin:2][256 lds-rows][32 k] (kwin-major keeps R1's zero-conflict
// swizzle: chunk' = chunk ^ ((row>>1)&3), staged via pre-swizzled global source).
// LDS row order is REGION-SORTED: A lds_row = miH*128 + wm*64 + mi*16 + lm, B = njH*128 + wn*32 + ...
// so each 8KB unit [kwin][miH/njH] is read in exactly ONE phase -> precise free/stage windows.
// Phase p: {ds_reads(cluster p), stage(slot p), barrier, 16 MFMA, [vmcnt(6) endP3/P7], barrier}.
// Clusters per K-tile: (miH,njH) = (0,0),(0,1),(1,0),(1,1). Stage slots (derived windows):
//   P0: (t+1).A[miH1]x2   P1: (t+2).A[miH0]x2   P2: (t+2).B[njH0]x2   P3: (t+2).B[njH1]x2
//   P4: (t+2).A[miH1]x2   P5: (t+3).A[miH0]x2   P6: (t+3).B[njH0]x2   P7: (t+3).B[njH1]x2
// vmcnt(6) at end of P3 (guarantees stages <=P0 landed, for P4-P7 reads) and end of P7 (<=P4,
// for next-iter P0-P3 reads); each sits BEFORE the trailing barrier -> cross-wave safe.
template<int MODE>
__global__ __launch_bounds__(512, 2) void gemm8p(
    const u16* __restrict__ A, const u16* __restrict__ BT,
    const float* __restrict__ b0, const float* __restrict__ b1, const float* __restrict__ b2,
    const u16* __restrict__ resid, u16* __restrict__ C, const int ldC, const int NB){
  __shared__ __attribute__((aligned(16))) char lds[131072];
  const int nwg = gridDim.x;
  const int orig = blockIdx.x;
  const int wg = ((nwg & 7)==0) ? ((orig&7)*(nwg>>3) + (orig>>3)) : orig;
  const int nblk = wg % NB, mblk = wg / NB;
  const int m0 = mblk<<8, n0 = nblk<<8;
  const int tid = threadIdx.x;
  const int wid = tid>>6, l = tid&63;
  const int lm = l&15, quad = l>>4;
  const int wm = wid>>2, wn = wid&3;

  // ---- staging: per-thread pre-swizzled global source; linear LDS dest (wave-uniform + lane*16)
  const int cg = (l&3) ^ ((l>>3)&3);
  const char* aSrc = (const char*)A  + ((size_t)(m0 + (wid>>2)*128 + (wid&3)*16 + (l>>2)))*1024 + cg*16;
  const char* bSrc = (const char*)BT + ((size_t)(n0 + (wid>>1)*64  + (wid&1)*16 + (l>>2)))*1024 + cg*16;
  char* ldsAs = lds + wid*1024;
  char* ldsBs = lds + 65536 + wid*1024;

#define STGA(kt, kw, mh) async16(aSrc + (mh)*65536 + (kt)*128 + (kw)*64, \
                                 ldsAs + (((kt)&1)*32768) + (kw)*16384 + (mh)*8192)
#define STGB(kt, kw, nh) async16(bSrc + (nh)*32768 + (kt)*128 + (kw)*64, \
                                 ldsBs + (((kt)&1)*32768) + (kw)*16384 + (nh)*8192)

  f32x4 acc[8][4];
  #pragma unroll
  for (int i=0;i<8;i++)
    #pragma unroll
    for (int j=0;j<4;j++){ f32x4 z = {0.f,0.f,0.f,0.f}; acc[i][j] = z; }

  // ---- fragment-read bases (verified zero-conflict swizzle) ----
  const int csw = (quad ^ ((l>>1)&3))*16;
  const char* aRd = lds + wm*4096 + lm*64 + csw;
  const char* bRd = lds + 65536 + wn*2048 + lm*64 + csw;

  frag8 a[4][2], bR[2][2][2];

  // ---- prologue: tile0 full (8 loads) + tile1 partial (6); vmcnt(6) -> tile0 landed ----
  STGA(0,0,0); STGA(0,1,0); STGB(0,0,0); STGB(0,1,0); STGB(0,0,1); STGB(0,1,1); STGA(0,0,1); STGA(0,1,1);
  STGA(1,0,0); STGA(1,1,0); STGB(1,0,0); STGB(1,1,0); STGB(1,0,1); STGB(1,1,1);
  asm volatile("s_waitcnt vmcnt(6)" ::: "memory");
  __builtin_amdgcn_s_barrier();

#define RDA(BUF, MH) { _Pragma("unroll") for (int mi_=0;mi_<4;mi_++){ \
    a[mi_][0] = *(const frag8*)(aRd + (BUF)*32768 + (MH)*8192 + mi_*1024); \
    a[mi_][1] = *(const frag8*)(aRd + (BUF)*32768 + 16384 + (MH)*8192 + mi_*1024); } }
#define RDB(BUF, NH) { _Pragma("unroll") for (int nj_=0;nj_<2;nj_++){ \
    bR[NH][nj_][0] = *(const frag8*)(bRd + (BUF)*32768 + (NH)*8192 + nj_*1024); \
    bR[NH][nj_][1] = *(const frag8*)(bRd + (BUF)*32768 + 16384 + (NH)*8192 + nj_*1024); } }
#define MM(MH, NH) { __builtin_amdgcn_s_setprio(1); \
  _Pragma("unroll") for (int kw_=0;kw_<2;kw_++) \
  _Pragma("unroll") for (int mi_=0;mi_<4;mi_++) \
  _Pragma("unroll") for (int nj_=0;nj_<2;nj_++) \
    acc[(MH)*4+mi_][(NH)*2+nj_] = __builtin_amdgcn_mfma_f32_16x16x32_bf16( \
        a[mi_][kw_], bR[NH][nj_][kw_], acc[(MH)*4+mi_][(NH)*2+nj_], 0,0,0); \
  __builtin_amdgcn_s_setprio(0); }
#define BAR __builtin_amdgcn_s_barrier()

#define ITER(T, FULL) { \
  /* P0 */ RDA(((T)&1),0); RDB(((T)&1),0); STGA((T)+1,0,1); STGA((T)+1,1,1); \
           BAR; MM(0,0); BAR; \
  /* P1 */ RDB(((T)&1),1); if (FULL){ STGA((T)+2,0,0); STGA((T)+2,1,0); } \
           BAR; MM(0,1); BAR; \
  /* P2 */ RDA(((T)&1),1); if (FULL){ STGB((T)+2,0,0); STGB((T)+2,1,0); } \
           BAR; MM(1,0); BAR; \
  /* P3 */ if (FULL){ STGB((T)+2,0,1); STGB((T)+2,1,1); } \
           BAR; MM(1,1); \
           if (FULL){ asm volatile("s_waitcnt vmcnt(6)" ::: "memory"); } \
           else     { asm volatile("s_waitcnt vmcnt(0)" ::: "memory"); } \
           BAR; \
  /* P4 */ RDA((((T)+1)&1),0); RDB((((T)+1)&1),0); if (FULL){ STGA((T)+2,0,1); STGA((T)+2,1,1); } \
           BAR; MM(0,0); BAR; \
  /* P5 */ RDB((((T)+1)&1),1); if (FULL){ STGA((T)+3,0,0); STGA((T)+3,1,0); } \
           BAR; MM(0,1); BAR; \
  /* P6 */ RDA((((T)+1)&1),1); if (FULL){ STGB((T)+3,0,0); STGB((T)+3,1,0); } \
           BAR; MM(1,0); BAR; \
  /* P7 */ if (FULL){ STGB((T)+3,0,1); STGB((T)+3,1,1); } \
           BAR; MM(1,1); \
           if (FULL){ asm volatile("s_waitcnt vmcnt(6)" ::: "memory"); } \
           BAR; \
}

  ITER(0,1)
  ITER(2,1)
  ITER(4,1)
  ITER(6,0)

#undef ITER
#undef BAR
#undef MM
#undef RDB
#undef RDA
#undef STGB
#undef STGA

  // ---- epilogue: bias (+residual) + bf16 store (layout identical to R1-verified) ----
  float bias[4]; int cols[4];
  #pragma unroll
  for (int nj=0;nj<4;nj++){
    const int c = n0 + wn*64 + nj*16 + lm;
    cols[nj] = c;
    if (MODE==0) bias[nj] = (c<512 ? b0[c] : (c<1024 ? b1[c-512] : b2[c-1024]));
    else         bias[nj] = b0[c];
  }
  #pragma unroll
  for (int mi=0; mi<8; mi++){
    const int rbase = m0 + wm*128 + mi*16 + quad*4;
    #pragma unroll
    for (int r=0;r<4;r++){
      const size_t row = (size_t)(rbase + r);
      #pragma unroll
      for (int nj=0;nj<4;nj++){
        float v = acc[mi][nj][r] + bias[nj];
        if (MODE==1) v += bf1(resid[row*FDIM + cols[nj]]);
        C[row*(size_t)ldC + cols[nj]] = f2bf(v);
      }
    }
  }
}

// -------------------- per-token head-attention + residual(bf16) + LN1 (1 wave = 1 token) --------------------
__global__ __launch_bounds__(256) void attn_ln1(const u16* __restrict__ qkvb,
    const u16* __restrict__ xb, const float* __restrict__ gam, const float* __restrict__ bet,
    u16* __restrict__ y1b){
  __shared__ __attribute__((aligned(16))) u16 sQ[4][1536];
  __shared__ float sWt[4][64];
  const int tid = threadIdx.x, w = tid>>6, l = tid&63;
  const int t = blockIdx.x*4 + w;
  {
    const int4* src = (const int4*)(qkvb + (size_t)t*1536);
    int4* dst = (int4*)(&sQ[w][0]);
    #pragma unroll
    for (int i=0;i<3;i++) dst[i*64 + l] = src[i*64 + l];
  }
  __syncthreads();
  const int h = l>>3, g = l&7;
  const u16* qrow = &sQ[w][h*64];
  const u16* krow = &sQ[w][512 + g*64];
  float sc = 0.f;
  const int dstart = (l&31)*2;
  #pragma unroll
  for (int i=0;i<32;i++){
    const int d = (dstart + 2*i) & 63;
    const uint32_t qp = *(const uint32_t*)(qrow + d);
    const uint32_t kp = *(const uint32_t*)(krow + d);
    sc += bflo(qp)*bflo(kp) + bfhi(qp)*bfhi(kp);
  }
  float mx = sc;
  mx = fmaxf(mx, __shfl_xor(mx,1));
  mx = fmaxf(mx, __shfl_xor(mx,2));
  mx = fmaxf(mx, __shfl_xor(mx,4));
  const float e = __expf(sc - mx);
  float ssum = e;
  ssum += __shfl_xor(ssum,1);
  ssum += __shfl_xor(ssum,2);
  ssum += __shfl_xor(ssum,4);
  sWt[w][l] = e / ssum;
  __syncthreads();
  float wt[8];
  #pragma unroll
  for (int gg=0;gg<8;gg++) wt[gg] = sWt[w][h*8+gg];
  float att[8] = {0,0,0,0,0,0,0,0};
  const int d0 = (l&7)*8;
  #pragma unroll
  for (int gg=0;gg<8;gg++){
    const int4 vv = *(const int4*)(&sQ[w][1024 + gg*64 + d0]);
    const uint32_t* vp = (const uint32_t*)&vv;
    #pragma unroll
    for (int p=0;p<4;p++){
      att[2*p]   += wt[gg]*bflo(vp[p]);
      att[2*p+1] += wt[gg]*bfhi(vp[p]);
    }
  }
  const size_t rb = (size_t)t*FDIM + l*8;
  const int4 xv = *(const int4*)(xb + rb);
  const uint32_t* xp = (const uint32_t*)&xv;
  float y[8]; float s1=0.f, s2=0.f;
  #pragma unroll
  for (int p=0;p<4;p++){
    y[2*p]   = att[2*p]   + bflo(xp[p]);
    y[2*p+1] = att[2*p+1] + bfhi(xp[p]);
  }
  #pragma unroll
  for (int j=0;j<8;j++){ s1 += y[j]; s2 += y[j]*y[j]; }
  #pragma unroll
  for (int off=1; off<64; off<<=1){ s1 += __shfl_xor(s1,off); s2 += __shfl_xor(s2,off); }
  const float mean = s1*(1.f/512.f);
  const float var  = s2*(1.f/512.f) - mean*mean;
  const float rstd = rsqrtf(var + 1e-5f);
  const float4 g0 = *(const float4*)(gam + l*8);
  const float4 g1v = *(const float4*)(gam + l*8 + 4);
  const float4 b0v = *(const float4*)(bet + l*8);
  const float4 b1v = *(const float4*)(bet + l*8 + 4);
  float of[8];
  of[0]=(y[0]-mean)*rstd*g0.x + b0v.x;
  of[1]=(y[1]-mean)*rstd*g0.y + b0v.y;
  of[2]=(y[2]-mean)*rstd*g0.z + b0v.z;
  of[3]=(y[3]-mean)*rstd*g0.w + b0v.w;
  of[4]=(y[4]-mean)*rstd*g1v.x + b1v.x;
  of[5]=(y[5]-mean)*rstd*g1v.y + b1v.y;
  of[6]=(y[6]-mean)*rstd*g1v.z + b1v.z;
  of[7]=(y[7]-mean)*rstd*g1v.w + b1v.w;
  u16 ob[8] __attribute__((aligned(16)));
  #pragma unroll
  for (int j=0;j<8;j++) ob[j] = f2bf(of[j]);
  *(int4*)(y1b + rb) = *(const int4*)ob;
}

// -------------------- LN2 over z (bf16); writes bf16 xb (next layer) or fp32 out --------------------
__global__ __launch_bounds__(256) void ln2_kernel(const u16* __restrict__ z,
    const float* __restrict__ gam, const float* __restrict__ bet,
    u16* __restrict__ xb, float* __restrict__ outp, const int final_){
  const int tid = threadIdx.x, w = tid>>6, l = tid&63;
  const int t = blockIdx.x*4 + w;
  const size_t rb = (size_t)t*FDIM + l*8;
  const int4 zv = *(const int4*)(z + rb);
  const uint32_t* zp = (const uint32_t*)&zv;
  float y[8];
  #pragma unroll
  for (int p=0;p<4;p++){ y[2*p]=bflo(zp[p]); y[2*p+1]=bfhi(zp[p]); }
  float s1=0.f, s2=0.f;
  #pragma unroll
  for (int j=0;j<8;j++){ s1+=y[j]; s2+=y[j]*y[j]; }
  #pragma unroll
  for (int off=1; off<64; off<<=1){ s1 += __shfl_xor(s1,off); s2 += __shfl_xor(s2,off); }
  const float mean = s1*(1.f/512.f);
  const float var  = s2*(1.f/512.f) - mean*mean;
  const float rstd = rsqrtf(var + 1e-5f);
  const float4 g0 = *(const float4*)(gam + l*8);
  const float4 g1v = *(const float4*)(gam + l*8 + 4);
  const float4 b0v = *(const float4*)(bet + l*8);
  const float4 b1v = *(const float4*)(bet + l*8 + 4);
  float of[8];
  of[0]=(y[0]-mean)*rstd*g0.x + b0v.x;
  of[1]=(y[1]-mean)*rstd*g0.y + b0v.y;
  of[2]=(y[2]-mean)*rstd*g0.z + b0v.z;
  of[3]=(y[3]-mean)*rstd*g0.w + b0v.w;
  of[4]=(y[4]-mean)*rstd*g1v.x + b1v.x;
  of[5]=(y[5]-mean)*rstd*g1v.y + b1v.y;
  of[6]=(y[6]-mean)*rstd*g1v.z + b1v.z;
  of[7]=(y[7]-mean)*rstd*g1v.w + b1v.w;
  if (final_){
    float4 o0; o0.x=of[0]; o0.y=of[1]; o0.z=of[2]; o0.w=of[3];
    float4 o1; o1.x=of[4]; o1.y=of[5]; o1.z=of[6]; o1.w=of[7];
    *(float4*)(outp + rb) = o0;
    *(float4*)(outp + rb + 4) = o1;
  } else {
    u16 ob[8] __attribute__((aligned(16)));
    #pragma unroll
    for (int j=0;j<8;j++) ob[j] = f2bf(of[j]);
    *(int4*)(xb + rb) = *(const int4*)ob;
  }
}

extern "C" void kernel_launch(void* const* d_in, const int* in_sizes, int n_in,
                              void* d_out, int out_size, void* d_ws, size_t ws_size,
                              hipStream_t stream){
  const int*   text = (const int*)d_in[0];
  const float* emb = (const float*)d_in[1];
  const float* pe  = (const float*)d_in[2];
  const float* Wq  = (const float*)d_in[3];
  const float* bq  = (const float*)d_in[4];
  const float* Wk  = (const float*)d_in[5];
  const float* bk  = (const float*)d_in[6];
  const float* Wv  = (const float*)d_in[7];
  const float* bv  = (const float*)d_in[8];
  const float* g1  = (const float*)d_in[9];
  const float* be1 = (const float*)d_in[10];
  const float* Wf  = (const float*)d_in[11];
  const float* bf_ = (const float*)d_in[12];
  const float* g2  = (const float*)d_in[13];
  const float* be2 = (const float*)d_in[14];
  float* outp = (float*)d_out;               // reference output dtype = float32

  // ---- layout: WT 12.6 MB + per-token {xb 1024 + y1b 1024 + qkv 3072} = 5120 B
  const size_t wtB = (size_t)6*2048*512*2;
  int T = NTOK;
  while (T > 2048 && wtB + (size_t)T*5120 > ws_size) T >>= 1;

  char* ws = (char*)d_ws;
  u16*   WT  = (u16*)ws;
  char*  act = ws + wtB;
  u16*   xb  = (u16*)act;                       // T*1024 B
  u16*   y1b = (u16*)(act + (size_t)T*1024);    // T*1024 B
  u16*   qkv = (u16*)(act + (size_t)T*2048);    // T*3072 B
  u16*   zb  = qkv;                             // alias: qkv dead once attn_ln1 ran

  hipLaunchKernelGGL(transpose_w, dim3(3072), dim3(256), 0, stream, Wq, Wk, Wv, Wf, WT);

  const int chunks = NTOK / T;
  for (int c = 0; c < chunks; c++){
    const int tok0 = c*T;
    hipLaunchKernelGGL(embed_kernel, dim3(T/2), dim3(256), 0, stream, text, emb, pe, xb, tok0);
    for (int lay=0; lay<6; lay++){
      const u16* WTl = WT + (size_t)lay*2048*FDIM;
      hipLaunchKernelGGL((gemm8p<0>), dim3((T/256)*6), dim3(512), 0, stream,
          xb, WTl, bq + lay*FDIM, bk + lay*FDIM, bv + lay*FDIM, (const u16*)nullptr, qkv, 1536, 6);
      hipLaunchKernelGGL(attn_ln1, dim3(T/4), dim3(256), 0, stream,
          qkv, xb, g1 + lay*FDIM, be1 + lay*FDIM, y1b);
      hipLaunchKernelGGL((gemm8p<1>), dim3((T/256)*2), dim3(512), 0, stream,
          y1b, WTl + (size_t)1536*FDIM, bf_ + lay*FDIM, (const float*)nullptr, (const float*)nullptr,
          y1b, zb, 512, 2);
      hipLaunchKernelGGL(ln2_kernel, dim3(T/4), dim3(256), 0, stream,
          zb, g2 + lay*FDIM, be2 + lay*FDIM, xb, outp + (size_t)tok0*FDIM, (lay==5)?1:0);
    }
  }
}